// Round 8
// baseline (91.663 us; speedup 1.0000x reference)
//
#include <hip/hip_runtime.h>
#include <math.h>

// Problem constants (fixed by setup_inputs).
#define CC 4
#define NN 4096                  // vertices per class (== queries per class)
#define MM 4096
#define DD 32
#define GR 10                    // grid resolution per axis
#define NCELL (GR * GR * GR)     // 1000 cells per class
#define CAP 16                   // bucket capacity (P(Poisson(4.1)>16)~1e-6/cell)
#define LPQ 16                   // lanes cooperating per query
#define BBLK 256
#define QBLK 256
#define MAING (CC * NCELL * CAP) // 64000 main query-groups
#define TAILG 256                // spill-query groups (normally all idle)

// ws layout (bytes):
//   vcnt  u32[CC*NCELL]          @ 0        (16000)
//   qcnt  u32[CC*NCELL]          @ 16000    (16000)
//   vSpillCnt u32[CC]            @ 32000    (16)
//   qSpillCnt u32[CC]            @ 32016    (16)   <- memset covers [0,32032)
//   vbuckets float4[CC*NCELL*CAP] @ 32768   (1024000)
//   qbuckets float4[CC*NCELL*CAP] @ 1056768 (1024000)
//   vspill  float4[CC*NN]        @ 2080768  (262144)
//   qspill  float4[CC*NN]        @ 2342912  (262144)
#define WS_ZERO_BYTES 32032
#define WS_QCNT      16000
#define WS_VSPILLCNT 32000
#define WS_QSPILLCNT 32016
#define WS_VBUCKETS  32768
#define WS_QBUCKETS  1056768
#define WS_VSPILL    2080768
#define WS_QSPILL    2342912

__device__ __forceinline__ int cellof(float x) {
    int c = (int)(x * (float)GR);
    return min(max(c, 0), GR - 1);
}

// Branchless sorted-insert of (d, j) into top-3 (d0<=d1<=d2). Strict <
// keeps earlier entries on ties (matches jax top_k tie-break).
__device__ __forceinline__ void ins3b(float d, int j,
                                      float& d0, float& d1, float& d2,
                                      int& i0, int& i1, int& i2) {
    bool l2 = d < d2, l1 = d < d1, l0 = d < d0;
    d2 = l1 ? d1 : (l2 ? d : d2);
    i2 = l1 ? i1 : (l2 ? j : i2);
    d1 = l0 ? d0 : (l1 ? d : d1);
    i1 = l0 ? i0 : (l1 ? j : i1);
    d0 = l0 ? d : d0;
    i0 = l0 ? j : i0;
}

// One-phase, device-wide build of BOTH vertex and query cell-buckets.
// Threads 0..16383 -> vertices, 16384..32767 -> queries. One atomic + one
// store per point; no scan, no block cooperation.
__global__ __launch_bounds__(BBLK) void k_build(
    const float* __restrict__ verts,      // [CC,NN,3]
    const float* __restrict__ nverts,     // [CC,MM,3]
    unsigned* __restrict__ ws32)          // base of ws (u32 view)
{
    const int gid = blockIdx.x * BBLK + threadIdx.x;   // 0..2*CC*NN-1
    const bool isQ = gid >= CC * NN;
    const int i = gid & (CC * NN - 1);
    const int c = i >> 12;

    const float* src = isQ ? nverts : verts;
    unsigned* cnt      = ws32 + (isQ ? WS_QCNT / 4 : 0);
    unsigned* spillCnt = ws32 + (isQ ? WS_QSPILLCNT / 4 : WS_VSPILLCNT / 4);
    float4* buckets = (float4*)((char*)ws32 + (isQ ? WS_QBUCKETS : WS_VBUCKETS));
    float4* spill   = (float4*)((char*)ws32 + (isQ ? WS_QSPILL   : WS_VSPILL));

    const float x = src[3 * i], y = src[3 * i + 1], z = src[3 * i + 2];
    const int cell = c * NCELL + (cellof(x) * GR + cellof(y)) * GR + cellof(z);
    const float4 p = make_float4(x, y, z, __int_as_float(i & (NN - 1)));
    const unsigned pos = atomicAdd(&cnt[cell], 1u);
    if (pos < CAP) {
        buckets[(size_t)cell * CAP + pos] = p;
    } else {                               // ~never (exactness fallback)
        const unsigned s = atomicAdd(&spillCnt[c], 1u);
        spill[(size_t)c * NN + s] = p;
    }
}

// Full query processing for one (c, query) by a 16-lane group; lane index t.
__device__ __forceinline__ void process_query(
    int c, int t, float qx, float qy, float qz, int orig,
    const float2* __restrict__ feat2,
    const unsigned* __restrict__ vcnt,
    const float4* __restrict__ vbuckets,
    const float4* __restrict__ vspill, unsigned vsc,
    float2* __restrict__ out2)
{
    const int cx = cellof(qx), cy = cellof(qy), cz = cellof(qz);
    const int offb = (c == 0) ? NN : (-c * NN);   // off-block 1.0 seed indices
    const float cs = 1.0f / (float)GR;
    const int cbase = c * NCELL;

    float d0 = 1.0f, d1 = 1.0f, d2 = 1.0f;
    int   i0 = offb, i1 = offb + 1, i2 = offb + 2;

    // step 1: all 27 neighbor-cell counts (independent loads).
    unsigned cnts[27];
    #pragma unroll
    for (int k = 0; k < 27; ++k) {
        const int px = cx + k / 9 - 1;
        const int py = cy + (k / 3) % 3 - 1;
        const int pz = cz + k % 3 - 1;
        const bool ok = (px >= 0) & (px < GR) & (py >= 0) & (py < GR) &
                        (pz >= 0) & (pz < GR);
        const int cid = ok ? (cbase + (px * GR + py) * GR + pz) : cbase;
        const unsigned v = vcnt[cid];
        cnts[k] = ok ? min(v, (unsigned)CAP) : 0u;
    }

    // step 2: 27 count-clamped point loads (batched 9 at a time).
    #pragma unroll
    for (int b = 0; b < 3; ++b) {
        float4 P[9];
        #pragma unroll
        for (int j = 0; j < 9; ++j) {
            const int k = b * 9 + j;
            const int px = cx + k / 9 - 1;
            const int py = cy + (k / 3) % 3 - 1;
            const int pz = cz + k % 3 - 1;
            const bool ok = (px >= 0) & (px < GR) & (py >= 0) & (py < GR) &
                            (pz >= 0) & (pz < GR);
            const int cid = ok ? (cbase + (px * GR + py) * GR + pz) : cbase;
            const unsigned ls = ((unsigned)t < cnts[k]) ? (unsigned)t : 0u;
            P[j] = vbuckets[(size_t)cid * CAP + ls];
        }
        #pragma unroll
        for (int j = 0; j < 9; ++j) {
            const int k = b * 9 + j;
            const float dx = P[j].x - qx, dy = P[j].y - qy, dz = P[j].z - qz;
            float dd = fmaf(dx, dx, fmaf(dy, dy, dz * dz));
            dd = ((unsigned)t < cnts[k]) ? dd : 1e30f;
            ins3b(dd, __float_as_int(P[j].w), d0, d1, d2, i0, i1, i2);
        }
    }
    // Vertex-spill points (lane-strided: each candidate in exactly one lane).
    for (unsigned s = (unsigned)t; s < vsc; s += LPQ) {
        const float4 p = vspill[(size_t)c * NN + s];
        const float dx = p.x - qx, dy = p.y - qy, dz = p.z - qz;
        const float dd = fmaf(dx, dx, fmaf(dy, dy, dz * dz));
        ins3b(dd, __float_as_int(p.w), d0, d1, d2, i0, i1, i2);
    }

    // Merge sorted triples across the 16-lane group.
    #pragma unroll
    for (int mask = 1; mask < LPQ; mask <<= 1) {
        const float e0 = __shfl_xor(d0, mask);
        const float e1 = __shfl_xor(d1, mask);
        const float e2 = __shfl_xor(d2, mask);
        const int   j0 = __shfl_xor(i0, mask);
        const int   j1 = __shfl_xor(i1, mask);
        const int   j2 = __shfl_xor(i2, mask);
        ins3b(e0, j0, d0, d1, d2, i0, i1, i2);
        ins3b(e1, j1, d0, d1, d2, i0, i1, i2);
        ins3b(e2, j2, d0, d1, d2, i0, i1, i2);
    }

    // Certificate for r=1 (group-uniform).
    {
        const int lx = max(cx - 1, 0), hx = min(cx + 1, GR - 1);
        const int ly = max(cy - 1, 0), hy = min(cy + 1, GR - 1);
        const int lz = max(cz - 1, 0), hz = min(cz + 1, GR - 1);
        float rmin = 1e30f;
        if (lx > 0)      rmin = fminf(rmin, qx - (float)lx * cs);
        if (hx < GR - 1) rmin = fminf(rmin, (float)(hx + 1) * cs - qx);
        if (ly > 0)      rmin = fminf(rmin, qy - (float)ly * cs);
        if (hy < GR - 1) rmin = fminf(rmin, (float)(hy + 1) * cs - qy);
        if (lz > 0)      rmin = fminf(rmin, qz - (float)lz * cs);
        if (hz < GR - 1) rmin = fminf(rmin, (float)(hz + 1) * cs - qz);

        if (!(d2 <= rmin * rmin)) {
            // Rare (P ~ 5.8e-6/query): expanding exact rescan from seeds.
            for (int r = 2;; ++r) {
                d0 = d1 = d2 = 1.0f;
                i0 = offb; i1 = offb + 1; i2 = offb + 2;
                const int Lx = max(cx - r, 0), Hx = min(cx + r, GR - 1);
                const int Ly = max(cy - r, 0), Hy = min(cy + r, GR - 1);
                const int Lz = max(cz - r, 0), Hz = min(cz + r, GR - 1);
                for (int px = Lx; px <= Hx; ++px) {
                    for (int py = Ly; py <= Hy; ++py) {
                        for (int pz = Lz; pz <= Hz; ++pz) {
                            const int cid = cbase + (px * GR + py) * GR + pz;
                            const unsigned n = min(vcnt[cid], (unsigned)CAP);
                            if ((unsigned)t < n) {
                                const float4 p = vbuckets[(size_t)cid * CAP + t];
                                const float dx = p.x - qx, dy = p.y - qy,
                                            dz = p.z - qz;
                                const float dd =
                                    fmaf(dx, dx, fmaf(dy, dy, dz * dz));
                                ins3b(dd, __float_as_int(p.w),
                                      d0, d1, d2, i0, i1, i2);
                            }
                        }
                    }
                }
                for (unsigned s = (unsigned)t; s < vsc; s += LPQ) {
                    const float4 p = vspill[(size_t)c * NN + s];
                    const float dx = p.x - qx, dy = p.y - qy, dz = p.z - qz;
                    const float dd = fmaf(dx, dx, fmaf(dy, dy, dz * dz));
                    ins3b(dd, __float_as_int(p.w), d0, d1, d2, i0, i1, i2);
                }
                #pragma unroll
                for (int mask = 1; mask < LPQ; mask <<= 1) {
                    const float e0 = __shfl_xor(d0, mask);
                    const float e1 = __shfl_xor(d1, mask);
                    const float e2 = __shfl_xor(d2, mask);
                    const int   j0 = __shfl_xor(i0, mask);
                    const int   j1 = __shfl_xor(i1, mask);
                    const int   j2 = __shfl_xor(i2, mask);
                    ins3b(e0, j0, d0, d1, d2, i0, i1, i2);
                    ins3b(e1, j1, d0, d1, d2, i0, i1, i2);
                    ins3b(e2, j2, d0, d1, d2, i0, i1, i2);
                }
                float rm = 1e30f;
                if (Lx > 0)      rm = fminf(rm, qx - (float)Lx * cs);
                if (Hx < GR - 1) rm = fminf(rm, (float)(Hx + 1) * cs - qx);
                if (Ly > 0)      rm = fminf(rm, qy - (float)Ly * cs);
                if (Hy < GR - 1) rm = fminf(rm, (float)(Hy + 1) * cs - qy);
                if (Lz > 0)      rm = fminf(rm, qz - (float)Lz * cs);
                if (Hz < GR - 1) rm = fminf(rm, (float)(Hz + 1) * cs - qz);
                const bool full = (Lx == 0 && Ly == 0 && Lz == 0 &&
                                   Hx == GR - 1 && Hy == GR - 1 &&
                                   Hz == GR - 1);
                if (full || d2 <= rm * rm) break;
            }
        }
    }

    // Fused epilogue: softmax(-d) + weighted feature gather (float2/lane).
    float w1 = expf(d0 - d1);
    float w2 = expf(d0 - d2);
    const float inv = 1.0f / (1.0f + w1 + w2);
    const float w0 = inv;
    w1 *= inv; w2 *= inv;

    const float2 a = feat2[(size_t)(i0 + c * NN) * 16 + t];
    const float2 b = feat2[(size_t)(i1 + c * NN) * 16 + t];
    const float2 g = feat2[(size_t)(i2 + c * NN) * 16 + t];
    float2 o;
    o.x = w0 * a.x + w1 * b.x + w2 * g.x;
    o.y = w0 * a.y + w1 * b.y + w2 * g.y;
    out2[((size_t)(c << 12) + (size_t)orig) * 16 + t] = o;   // 128B contiguous
}

// Group G < MAING handles qbuckets[cell][slot] (cell-major order -> wave's
// groups share the same 27 neighbor buckets: L1 broadcast, no sort needed).
// Tail groups handle spilled queries (normally none).
__global__ __launch_bounds__(QBLK) void k_query(
    const float2* __restrict__ feat2,     // [CC*NN][16] float2
    const unsigned* __restrict__ ws32,    // base of ws (u32 view)
    float2* __restrict__ out2)            // [CC*MM][16] float2
{
    const int gid = blockIdx.x * QBLK + threadIdx.x;
    const int G = gid >> 4;
    const int t = gid & (LPQ - 1);

    const unsigned* vcnt = ws32;
    const unsigned* qcnt = ws32 + WS_QCNT / 4;
    const float4* vbuckets = (const float4*)((const char*)ws32 + WS_VBUCKETS);
    const float4* qbuckets = (const float4*)((const char*)ws32 + WS_QBUCKETS);
    const float4* vspill   = (const float4*)((const char*)ws32 + WS_VSPILL);
    const float4* qspill   = (const float4*)((const char*)ws32 + WS_QSPILL);
    const unsigned* vSpillCnt = ws32 + WS_VSPILLCNT / 4;
    const unsigned* qSpillCnt = ws32 + WS_QSPILLCNT / 4;

    if (G < MAING) {
        const int c    = G / (NCELL * CAP);
        const int rem  = G - c * (NCELL * CAP);
        const int cell = rem >> 4;          // CAP == 16
        const int slot = rem & (CAP - 1);
        const unsigned qn = min(qcnt[c * NCELL + cell], (unsigned)CAP);
        if ((unsigned)slot >= qn) return;   // idle group: one load, exit
        const float4 q = qbuckets[(size_t)(c * NCELL + cell) * CAP + slot];
        process_query(c, t, q.x, q.y, q.z, __float_as_int(q.w),
                      feat2, vcnt, vbuckets, vspill, vSpillCnt[c], out2);
    } else {
        const int tg = G - MAING;           // 0..TAILG-1 (cold path)
        const int c  = tg & (CC - 1);
        const unsigned sqn = qSpillCnt[c];
        for (unsigned s = (unsigned)(tg >> 2); s < sqn; s += TAILG / CC) {
            const float4 q = qspill[(size_t)c * NN + s];
            process_query(c, t, q.x, q.y, q.z, __float_as_int(q.w),
                          feat2, vcnt, vbuckets, vspill, vSpillCnt[c], out2);
        }
    }
}

extern "C" void kernel_launch(void* const* d_in, const int* in_sizes, int n_in,
                              void* d_out, int out_size, void* d_ws, size_t ws_size,
                              hipStream_t stream) {
    const float* feat   = (const float*)d_in[0];   // points_feat [1, C*N, D] f32
    const float* verts  = (const float*)d_in[1];   // vertices    [C, N, 3]  f32
    const float* nverts = (const float*)d_in[2];   // new_vertices[C, M, 3]  f32
    float* outp = (float*)d_out;                   // [1, C*M, D] f32

    hipMemsetAsync(d_ws, 0, WS_ZERO_BYTES, stream);
    k_build<<<dim3(2 * CC * NN / BBLK), dim3(BBLK), 0, stream>>>(
        verts, nverts, (unsigned*)d_ws);
    k_query<<<dim3((MAING + TAILG) * LPQ / QBLK), dim3(QBLK), 0, stream>>>(
        (const float2*)feat, (const unsigned*)d_ws, (float2*)outp);
}

// Round 9
// 76.304 us; speedup vs baseline: 1.2013x; 1.2013x over previous
//
#include <hip/hip_runtime.h>
#include <math.h>

// Problem constants (fixed by setup_inputs).
#define CC 4
#define NN 4096                  // vertices per class (== queries per class)
#define MM 4096
#define DD 32
#define GR 10                    // grid resolution per axis
#define NCELL (GR * GR * GR)     // 1000 cells per class
#define CAP 16                   // bucket capacity (overflow -> exact spill path)
#define LPQ 16                   // lanes cooperating per query
#define BBLK 256
#define QBLK 1024                // k_query block (64 queries per block)

// ws layout (bytes):
//   vcnt      u32[CC*NCELL]       @ 0        (16000)
//   vSpillCnt u32[CC]             @ 16000    (16)   <- memset covers [0,16016)
//   vbuckets  float4[CC*NCELL*CAP]@ 16384    (1024000)
//   vspill    float4[CC*NN]       @ 1048576  (262144)
#define WS_ZERO_BYTES 16016
#define WS_VSPILLCNT  16000
#define WS_VBUCKETS   16384
#define WS_VSPILL     (1 << 20)

__device__ __forceinline__ int cellof(float x) {
    int c = (int)(x * (float)GR);
    return min(max(c, 0), GR - 1);
}

// Branchless sorted-insert of (d, j) into top-3 (d0<=d1<=d2). Strict <
// keeps earlier entries on ties (matches jax top_k tie-break).
__device__ __forceinline__ void ins3b(float d, int j,
                                      float& d0, float& d1, float& d2,
                                      int& i0, int& i1, int& i2) {
    bool l2 = d < d2, l1 = d < d1, l0 = d < d0;
    d2 = l1 ? d1 : (l2 ? d : d2);
    i2 = l1 ? i1 : (l2 ? j : i2);
    d1 = l0 ? d0 : (l1 ? d : d1);
    i1 = l0 ? i0 : (l1 ? j : i1);
    d0 = l0 ? d : d0;
    i0 = l0 ? j : i0;
}

// One-phase device-wide vertex bucket build: one thread per vertex,
// one global atomic + one store. No scan, no block cooperation.
__global__ __launch_bounds__(BBLK) void k_build(
    const float* __restrict__ verts,      // [CC,NN,3]
    unsigned* __restrict__ vcnt,          // [CC*NCELL]
    unsigned* __restrict__ vSpillCnt,     // [CC]
    float4* __restrict__ vbuckets,        // [CC*NCELL][CAP]
    float4* __restrict__ vspill)          // [CC][NN]
{
    const int i = blockIdx.x * BBLK + threadIdx.x;   // 0..CC*NN-1
    const int c = i >> 12;
    const float x = verts[3 * i], y = verts[3 * i + 1], z = verts[3 * i + 2];
    const int cell = c * NCELL + (cellof(x) * GR + cellof(y)) * GR + cellof(z);
    const float4 p = make_float4(x, y, z, __int_as_float(i & (NN - 1)));
    const unsigned pos = atomicAdd(&vcnt[cell], 1u);
    if (pos < CAP) {
        vbuckets[(size_t)cell * CAP + pos] = p;
    } else {                               // ~never (exactness fallback)
        const unsigned s = atomicAdd(&vSpillCnt[c], 1u);
        vspill[(size_t)c * NN + s] = p;
    }
}

// One block per 64 queries (all same class). Block stages the class's
// compacted cell-sorted vertex set into LDS (SoA, 60 KB) via an LDS scan of
// the clamped counts + coalesced bucket reads; then 64 groups of 16 lanes
// answer queries from LDS (latency-free), natural order (coalesced output).
__global__ __launch_bounds__(QBLK) void k_query(
    const float2* __restrict__ feat2,     // [CC*NN][16] float2
    const float* __restrict__ nverts,     // [CC*MM*3]
    const unsigned* __restrict__ vcnt,    // [CC*NCELL]
    const unsigned* __restrict__ vSpillCnt,// [CC]
    const float4* __restrict__ vbuckets,  // [CC*NCELL][CAP]
    const float4* __restrict__ vspill,    // [CC][NN]
    float2* __restrict__ out2)            // [CC*MM][16] float2
{
    __shared__ float sx[NN], sy[NN], sz[NN];          // 48 KB
    __shared__ unsigned short sidx[NN];               // 8 KB
    __shared__ unsigned sstart[NCELL + 1];            // ~4 KB
    __shared__ unsigned wsum[QBLK / 64];

    const int tid = threadIdx.x;
    const int c   = blockIdx.x >> 6;                  // 64 blocks per class
    const int cbase = c * NCELL;

    // ---- Phase A: LDS exclusive scan of clamped counts -> sstart ----
    const unsigned own =
        (tid < NCELL) ? min(vcnt[cbase + tid], (unsigned)CAP) : 0u;
    const int lane = tid & 63, wid = tid >> 6;
    unsigned incl = own;
    #pragma unroll
    for (int off = 1; off < 64; off <<= 1) {
        unsigned v = __shfl_up(incl, off);
        if (lane >= off) incl += v;
    }
    if (lane == 63) wsum[wid] = incl;
    __syncthreads();
    unsigned wbase = 0;
    for (int w = 0; w < wid; ++w) wbase += wsum[w];
    if (tid < NCELL) sstart[tid] = wbase + incl - own;
    if (tid == QBLK - 1) sstart[NCELL] = wbase + incl;   // total (<= NN)
    __syncthreads();

    // ---- Phase B: compact buckets -> LDS (coalesced global reads) ----
    for (int k = tid; k < NCELL * CAP; k += QBLK) {
        const int cell = k >> 4, slot = k & (CAP - 1);
        const unsigned a = sstart[cell];
        const unsigned n = sstart[cell + 1] - a;
        if ((unsigned)slot < n) {
            const float4 p = vbuckets[(size_t)(cbase + cell) * CAP + slot];
            const unsigned pos = a + slot;
            sx[pos] = p.x; sy[pos] = p.y; sz[pos] = p.z;
            sidx[pos] = (unsigned short)__float_as_int(p.w);
        }
    }
    __syncthreads();

    // ---- Phase C: 64 queries, 16 lanes each ----
    const int g = tid >> 4;                    // group 0..63
    const int t = tid & (LPQ - 1);
    const int m = (blockIdx.x << 6) + g;       // global query slot
    const float qx = nverts[3 * m + 0];
    const float qy = nverts[3 * m + 1];
    const float qz = nverts[3 * m + 2];

    const int cx = cellof(qx), cy = cellof(qy), cz = cellof(qz);
    const int offb = (c == 0) ? NN : (-c * NN);   // off-block 1.0 seed indices
    const float cs = 1.0f / (float)GR;
    const unsigned vsc = vSpillCnt[c];

    float d0 = 1.0f, d1 = 1.0f, d2 = 1.0f;
    int   i0 = offb, i1 = offb + 1, i2 = offb + 2;

    const int lz = max(cz - 1, 0), hz = min(cz + 1, GR - 1);

    // 9 z-column ranges from LDS starts.
    unsigned aa[9], bb[9];
    #pragma unroll
    for (int j = 0; j < 9; ++j) {
        const int px = cx + j / 3 - 1, py = cy + j % 3 - 1;
        const bool ok = (px >= 0) & (px < GR) & (py >= 0) & (py < GR);
        const int rb = ok ? ((px * GR + py) * GR) : 0;
        const unsigned av = sstart[rb + lz];
        const unsigned bv = sstart[rb + hz + 1];
        aa[j] = av;
        bb[j] = ok ? bv : av;                  // empty if out of grid
    }

    // 2-deep predicated batch: lanes t and t+16 cover 32 pts/column.
    unsigned over = 0u;
    #pragma unroll
    for (int j = 0; j < 9; ++j) {
        const unsigned s0 = aa[j] + t, s1 = s0 + LPQ;
        const unsigned u0 = (s0 < bb[j]) ? s0 : 0u;
        const unsigned u1 = (s1 < bb[j]) ? s1 : 0u;
        const float x0 = sx[u0], y0 = sy[u0], z0 = sz[u0];
        const float x1 = sx[u1], y1 = sy[u1], z1 = sz[u1];
        const int j0 = sidx[u0], j1 = sidx[u1];
        float dx = x0 - qx, dy = y0 - qy, dz = z0 - qz;
        float dd = fmaf(dx, dx, fmaf(dy, dy, dz * dz));
        dd = (s0 < bb[j]) ? dd : 1e30f;
        ins3b(dd, j0, d0, d1, d2, i0, i1, i2);
        dx = x1 - qx; dy = y1 - qy; dz = z1 - qz;
        float de = fmaf(dx, dx, fmaf(dy, dy, dz * dz));
        de = (s1 < bb[j]) ? de : 1e30f;
        ins3b(de, j1, d0, d1, d2, i0, i1, i2);
        over |= (bb[j] - aa[j] > 2u * LPQ) ? 1u : 0u;
    }
    if (over) {                                // rare: columns > 32 pts
        #pragma unroll 1
        for (int j = 0; j < 9; ++j) {
            for (unsigned s = aa[j] + 2u * LPQ + t; s < bb[j]; s += LPQ) {
                const float dx = sx[s] - qx, dy = sy[s] - qy, dz = sz[s] - qz;
                const float dd = fmaf(dx, dx, fmaf(dy, dy, dz * dz));
                ins3b(dd, (int)sidx[s], d0, d1, d2, i0, i1, i2);
            }
        }
    }
    // Bucket-overflow spill points (global, normally zero; lane-strided).
    for (unsigned s = (unsigned)t; s < vsc; s += LPQ) {
        const float4 p = vspill[(size_t)c * NN + s];
        const float dx = p.x - qx, dy = p.y - qy, dz = p.z - qz;
        const float dd = fmaf(dx, dx, fmaf(dy, dy, dz * dz));
        ins3b(dd, __float_as_int(p.w), d0, d1, d2, i0, i1, i2);
    }

    // Merge sorted triples across the 16-lane group.
    #pragma unroll
    for (int mask = 1; mask < LPQ; mask <<= 1) {
        const float e0 = __shfl_xor(d0, mask);
        const float e1 = __shfl_xor(d1, mask);
        const float e2 = __shfl_xor(d2, mask);
        const int   j0 = __shfl_xor(i0, mask);
        const int   j1 = __shfl_xor(i1, mask);
        const int   j2 = __shfl_xor(i2, mask);
        ins3b(e0, j0, d0, d1, d2, i0, i1, i2);
        ins3b(e1, j1, d0, d1, d2, i0, i1, i2);
        ins3b(e2, j2, d0, d1, d2, i0, i1, i2);
    }

    // Certificate for r=1 (group-uniform); rare exact expanding rescan.
    {
        const int lx = max(cx - 1, 0), hx = min(cx + 1, GR - 1);
        const int ly = max(cy - 1, 0), hy = min(cy + 1, GR - 1);
        float rmin = 1e30f;
        if (lx > 0)      rmin = fminf(rmin, qx - (float)lx * cs);
        if (hx < GR - 1) rmin = fminf(rmin, (float)(hx + 1) * cs - qx);
        if (ly > 0)      rmin = fminf(rmin, qy - (float)ly * cs);
        if (hy < GR - 1) rmin = fminf(rmin, (float)(hy + 1) * cs - qy);
        if (lz > 0)      rmin = fminf(rmin, qz - (float)lz * cs);
        if (hz < GR - 1) rmin = fminf(rmin, (float)(hz + 1) * cs - qz);

        if (!(d2 <= rmin * rmin)) {            // P ~ 5.8e-6 per query
            for (int r = 2;; ++r) {
                d0 = d1 = d2 = 1.0f;
                i0 = offb; i1 = offb + 1; i2 = offb + 2;
                const int Lx = max(cx - r, 0), Hx = min(cx + r, GR - 1);
                const int Ly = max(cy - r, 0), Hy = min(cy + r, GR - 1);
                const int Lz = max(cz - r, 0), Hz = min(cz + r, GR - 1);
                for (int px = Lx; px <= Hx; ++px) {
                    for (int py = Ly; py <= Hy; ++py) {
                        for (int pz = Lz; pz <= Hz; ++pz) {
                            const int cid = (px * GR + py) * GR + pz;
                            const unsigned a = sstart[cid];
                            const unsigned n = sstart[cid + 1] - a;
                            if ((unsigned)t < n) {
                                const unsigned s = a + t;
                                const float dx = sx[s] - qx,
                                            dy = sy[s] - qy,
                                            dz = sz[s] - qz;
                                const float dd =
                                    fmaf(dx, dx, fmaf(dy, dy, dz * dz));
                                ins3b(dd, (int)sidx[s],
                                      d0, d1, d2, i0, i1, i2);
                            }
                        }
                    }
                }
                for (unsigned s = (unsigned)t; s < vsc; s += LPQ) {
                    const float4 p = vspill[(size_t)c * NN + s];
                    const float dx = p.x - qx, dy = p.y - qy, dz = p.z - qz;
                    const float dd = fmaf(dx, dx, fmaf(dy, dy, dz * dz));
                    ins3b(dd, __float_as_int(p.w), d0, d1, d2, i0, i1, i2);
                }
                #pragma unroll
                for (int mask = 1; mask < LPQ; mask <<= 1) {
                    const float e0 = __shfl_xor(d0, mask);
                    const float e1 = __shfl_xor(d1, mask);
                    const float e2 = __shfl_xor(d2, mask);
                    const int   j0 = __shfl_xor(i0, mask);
                    const int   j1 = __shfl_xor(i1, mask);
                    const int   j2 = __shfl_xor(i2, mask);
                    ins3b(e0, j0, d0, d1, d2, i0, i1, i2);
                    ins3b(e1, j1, d0, d1, d2, i0, i1, i2);
                    ins3b(e2, j2, d0, d1, d2, i0, i1, i2);
                }
                float rm = 1e30f;
                if (Lx > 0)      rm = fminf(rm, qx - (float)Lx * cs);
                if (Hx < GR - 1) rm = fminf(rm, (float)(Hx + 1) * cs - qx);
                if (Ly > 0)      rm = fminf(rm, qy - (float)Ly * cs);
                if (Hy < GR - 1) rm = fminf(rm, (float)(Hy + 1) * cs - qy);
                if (Lz > 0)      rm = fminf(rm, qz - (float)Lz * cs);
                if (Hz < GR - 1) rm = fminf(rm, (float)(Hz + 1) * cs - qz);
                const bool full = (Lx == 0 && Ly == 0 && Lz == 0 &&
                                   Hx == GR - 1 && Hy == GR - 1 &&
                                   Hz == GR - 1);
                if (full || d2 <= rm * rm) break;
            }
        }
    }

    // Fused epilogue: softmax(-d) + weighted feature gather (float2/lane).
    float w1 = expf(d0 - d1);
    float w2 = expf(d0 - d2);
    const float inv = 1.0f / (1.0f + w1 + w2);
    const float w0 = inv;
    w1 *= inv; w2 *= inv;

    const float2 a = feat2[(size_t)(i0 + c * NN) * 16 + t];
    const float2 b = feat2[(size_t)(i1 + c * NN) * 16 + t];
    const float2 gg = feat2[(size_t)(i2 + c * NN) * 16 + t];
    float2 o;
    o.x = w0 * a.x + w1 * b.x + w2 * gg.x;
    o.y = w0 * a.y + w1 * b.y + w2 * gg.y;
    out2[(size_t)m * 16 + t] = o;              // natural order -> coalesced
}

extern "C" void kernel_launch(void* const* d_in, const int* in_sizes, int n_in,
                              void* d_out, int out_size, void* d_ws, size_t ws_size,
                              hipStream_t stream) {
    const float* feat   = (const float*)d_in[0];   // points_feat [1, C*N, D] f32
    const float* verts  = (const float*)d_in[1];   // vertices    [C, N, 3]  f32
    const float* nverts = (const float*)d_in[2];   // new_vertices[C, M, 3]  f32
    float* outp = (float*)d_out;                   // [1, C*M, D] f32

    unsigned* vcnt      = (unsigned*)d_ws;
    unsigned* vSpillCnt = (unsigned*)((char*)d_ws + WS_VSPILLCNT);
    float4*   vbuckets  = (float4*)((char*)d_ws + WS_VBUCKETS);
    float4*   vspill    = (float4*)((char*)d_ws + WS_VSPILL);

    hipMemsetAsync(d_ws, 0, WS_ZERO_BYTES, stream);
    k_build<<<dim3(CC * NN / BBLK), dim3(BBLK), 0, stream>>>(
        verts, vcnt, vSpillCnt, vbuckets, vspill);
    k_query<<<dim3(CC * MM / 64), dim3(QBLK), 0, stream>>>(
        (const float2*)feat, nverts, vcnt, vSpillCnt, vbuckets, vspill,
        (float2*)outp);
}

// Round 10
// 67.080 us; speedup vs baseline: 1.3665x; 1.1375x over previous
//
#include <hip/hip_runtime.h>
#include <math.h>

// Problem constants (fixed by setup_inputs).
#define CC 4
#define NN 4096                  // vertices per class (== queries per class)
#define MM 4096
#define DD 32
#define GR 10                    // grid resolution per axis
#define NCELL (GR * GR * GR)     // 1000 cells per class
#define LPQ 16                   // lanes cooperating per query
#define BLK 1024                 // threads per block
#define QPB 64                   // queries per block

__device__ __forceinline__ int cellof(float x) {
    int c = (int)(x * (float)GR);
    return min(max(c, 0), GR - 1);
}

// Branchless sorted-insert of (d, j) into top-3 (d0<=d1<=d2). Strict <
// keeps earlier entries on ties (matches jax top_k tie-break).
__device__ __forceinline__ void ins3b(float d, int j,
                                      float& d0, float& d1, float& d2,
                                      int& i0, int& i1, int& i2) {
    bool l2 = d < d2, l1 = d < d1, l0 = d < d0;
    d2 = l1 ? d1 : (l2 ? d : d2);
    i2 = l1 ? i1 : (l2 ? j : i2);
    d1 = l0 ? d0 : (l1 ? d : d1);
    i1 = l0 ? i0 : (l1 ? j : i1);
    d0 = l0 ? d : d0;
    i0 = l0 ? j : i0;
}

// ONE kernel, ONE graph node, no workspace. Each block privately builds the
// full cell index of its class in LDS (48 KB of points + 8 KB idx + cell
// starts), then answers 64 queries from LDS. 64 blocks per class re-stage the
// same 192 KB of vertices -> L2 broadcast, ~free.
__global__ __launch_bounds__(BLK) void k_all(
    const float2* __restrict__ feat2,     // [CC*NN][16] float2
    const float* __restrict__ verts,      // [CC,NN,3]
    const float* __restrict__ nverts,     // [CC,MM,3]
    float2* __restrict__ out2)            // [CC*MM][16] float2
{
    __shared__ float sx[NN], sy[NN], sz[NN];   // 48 KB  (SoA, cell-sorted)
    __shared__ unsigned short sidx[NN];        // 8 KB   (local vertex idx)
    __shared__ unsigned cnt[NCELL];            // 4 KB   (counts -> cursor)
    __shared__ unsigned sstart[NCELL + 1];     // 4 KB   (exclusive starts)
    __shared__ unsigned wsum[BLK / 64];

    const int tid = threadIdx.x;
    const int c   = blockIdx.x >> 6;           // 64 blocks per class

    // ---- Phase A: stage 4 points/thread into registers ----
    if (tid < NCELL) cnt[tid] = 0u;
    const float4* src4 = (const float4*)(verts + (size_t)c * NN * 3);
    const float4 fa = src4[3 * tid];
    const float4 fb = src4[3 * tid + 1];
    const float4 fc = src4[3 * tid + 2];
    const float px[4] = {fa.x, fa.w, fb.z, fc.y};
    const float py[4] = {fa.y, fb.x, fb.w, fc.z};
    const float pz[4] = {fa.z, fb.y, fc.x, fc.w};
    __syncthreads();                           // cnt zeroed

    int cell[4];
    #pragma unroll
    for (int u = 0; u < 4; ++u) {
        cell[u] = (cellof(px[u]) * GR + cellof(py[u])) * GR + cellof(pz[u]);
        atomicAdd(&cnt[cell[u]], 1u);
    }
    __syncthreads();

    // ---- Phase B: exclusive scan of 1000 counts (thread t owns cell t) ----
    const int lane = tid & 63, wid = tid >> 6;
    const unsigned own = (tid < NCELL) ? cnt[tid] : 0u;
    unsigned incl = own;
    #pragma unroll
    for (int off = 1; off < 64; off <<= 1) {
        unsigned v = __shfl_up(incl, off);
        if (lane >= off) incl += v;
    }
    if (lane == 63) wsum[wid] = incl;
    __syncthreads();                           // also fences own= reads
    unsigned wbase = 0;
    for (int w = 0; w < wid; ++w) wbase += wsum[w];
    if (tid < NCELL) {
        const unsigned excl = wbase + incl - own;
        cnt[tid]    = excl;                    // scatter cursor
        sstart[tid] = excl;
    }
    if (tid == BLK - 1) sstart[NCELL] = wbase + incl;   // == NN
    __syncthreads();

    // ---- Phase C: scatter points into cell-sorted SoA ----
    #pragma unroll
    for (int u = 0; u < 4; ++u) {
        const unsigned pos = atomicAdd(&cnt[cell[u]], 1u);
        sx[pos] = px[u]; sy[pos] = py[u]; sz[pos] = pz[u];
        sidx[pos] = (unsigned short)(4 * tid + u);
    }
    __syncthreads();

    // ---- Phase D: 64 queries, 16 lanes each, all from LDS ----
    const int g = tid >> 4;                    // group 0..63
    const int t = tid & (LPQ - 1);
    const int m = (blockIdx.x << 6) + g;       // global query slot
    const float qx = nverts[3 * m + 0];
    const float qy = nverts[3 * m + 1];
    const float qz = nverts[3 * m + 2];

    const int cx = cellof(qx), cy = cellof(qy), cz = cellof(qz);
    const int offb = (c == 0) ? NN : (-c * NN);   // off-block 1.0 seed indices
    const float cs = 1.0f / (float)GR;

    float d0 = 1.0f, d1 = 1.0f, d2 = 1.0f;
    int   i0 = offb, i1 = offb + 1, i2 = offb + 2;

    const int lz = max(cz - 1, 0), hz = min(cz + 1, GR - 1);

    // 9 z-column ranges from LDS starts (broadcast within group).
    unsigned aa[9], bb[9];
    #pragma unroll
    for (int j = 0; j < 9; ++j) {
        const int ppx = cx + j / 3 - 1, ppy = cy + j % 3 - 1;
        const bool ok = (ppx >= 0) & (ppx < GR) & (ppy >= 0) & (ppy < GR);
        const int rb = ok ? ((ppx * GR + ppy) * GR) : 0;
        const unsigned av = sstart[rb + lz];
        const unsigned bv = sstart[rb + hz + 1];
        aa[j] = av;
        bb[j] = ok ? bv : av;                  // empty if out of grid
    }

    // 2-deep predicated batch: lanes t and t+16 cover 32 pts/column.
    unsigned over = 0u;
    #pragma unroll
    for (int j = 0; j < 9; ++j) {
        const unsigned s0 = aa[j] + t, s1 = s0 + LPQ;
        const unsigned u0 = (s0 < bb[j]) ? s0 : 0u;
        const unsigned u1 = (s1 < bb[j]) ? s1 : 0u;
        const float x0 = sx[u0], y0 = sy[u0], z0 = sz[u0];
        const float x1 = sx[u1], y1 = sy[u1], z1 = sz[u1];
        const int j0 = sidx[u0], j1 = sidx[u1];
        float dx = x0 - qx, dy = y0 - qy, dz = z0 - qz;
        float dd = fmaf(dx, dx, fmaf(dy, dy, dz * dz));
        dd = (s0 < bb[j]) ? dd : 1e30f;
        ins3b(dd, j0, d0, d1, d2, i0, i1, i2);
        dx = x1 - qx; dy = y1 - qy; dz = z1 - qz;
        float de = fmaf(dx, dx, fmaf(dy, dy, dz * dz));
        de = (s1 < bb[j]) ? de : 1e30f;
        ins3b(de, j1, d0, d1, d2, i0, i1, i2);
        over |= (bb[j] - aa[j] > 2u * LPQ) ? 1u : 0u;
    }
    if (over) {                                // rare: columns > 32 pts
        #pragma unroll 1
        for (int j = 0; j < 9; ++j) {
            for (unsigned s = aa[j] + 2u * LPQ + t; s < bb[j]; s += LPQ) {
                const float dx = sx[s] - qx, dy = sy[s] - qy, dz = sz[s] - qz;
                const float dd = fmaf(dx, dx, fmaf(dy, dy, dz * dz));
                ins3b(dd, (int)sidx[s], d0, d1, d2, i0, i1, i2);
            }
        }
    }

    // Merge sorted triples across the 16-lane group.
    #pragma unroll
    for (int mask = 1; mask < LPQ; mask <<= 1) {
        const float e0 = __shfl_xor(d0, mask);
        const float e1 = __shfl_xor(d1, mask);
        const float e2 = __shfl_xor(d2, mask);
        const int   j0 = __shfl_xor(i0, mask);
        const int   j1 = __shfl_xor(i1, mask);
        const int   j2 = __shfl_xor(i2, mask);
        ins3b(e0, j0, d0, d1, d2, i0, i1, i2);
        ins3b(e1, j1, d0, d1, d2, i0, i1, i2);
        ins3b(e2, j2, d0, d1, d2, i0, i1, i2);
    }

    // Certificate for r=1 (group-uniform); rare exact expanding rescan.
    {
        const int lx = max(cx - 1, 0), hx = min(cx + 1, GR - 1);
        const int ly = max(cy - 1, 0), hy = min(cy + 1, GR - 1);
        float rmin = 1e30f;
        if (lx > 0)      rmin = fminf(rmin, qx - (float)lx * cs);
        if (hx < GR - 1) rmin = fminf(rmin, (float)(hx + 1) * cs - qx);
        if (ly > 0)      rmin = fminf(rmin, qy - (float)ly * cs);
        if (hy < GR - 1) rmin = fminf(rmin, (float)(hy + 1) * cs - qy);
        if (lz > 0)      rmin = fminf(rmin, qz - (float)lz * cs);
        if (hz < GR - 1) rmin = fminf(rmin, (float)(hz + 1) * cs - qz);

        if (!(d2 <= rmin * rmin)) {            // P ~ 5.8e-6 per query
            for (int r = 2;; ++r) {
                d0 = d1 = d2 = 1.0f;
                i0 = offb; i1 = offb + 1; i2 = offb + 2;
                const int Lx = max(cx - r, 0), Hx = min(cx + r, GR - 1);
                const int Ly = max(cy - r, 0), Hy = min(cy + r, GR - 1);
                const int Lz = max(cz - r, 0), Hz = min(cz + r, GR - 1);
                for (int ppx = Lx; ppx <= Hx; ++ppx) {
                    for (int ppy = Ly; ppy <= Hy; ++ppy) {
                        const int rb = (ppx * GR + ppy) * GR;
                        const unsigned a = sstart[rb + Lz];
                        const unsigned b = sstart[rb + Hz + 1];
                        for (unsigned s = a + t; s < b; s += LPQ) {
                            const float dx = sx[s] - qx, dy = sy[s] - qy,
                                        dz = sz[s] - qz;
                            const float dd =
                                fmaf(dx, dx, fmaf(dy, dy, dz * dz));
                            ins3b(dd, (int)sidx[s], d0, d1, d2, i0, i1, i2);
                        }
                    }
                }
                #pragma unroll
                for (int mask = 1; mask < LPQ; mask <<= 1) {
                    const float e0 = __shfl_xor(d0, mask);
                    const float e1 = __shfl_xor(d1, mask);
                    const float e2 = __shfl_xor(d2, mask);
                    const int   j0 = __shfl_xor(i0, mask);
                    const int   j1 = __shfl_xor(i1, mask);
                    const int   j2 = __shfl_xor(i2, mask);
                    ins3b(e0, j0, d0, d1, d2, i0, i1, i2);
                    ins3b(e1, j1, d0, d1, d2, i0, i1, i2);
                    ins3b(e2, j2, d0, d1, d2, i0, i1, i2);
                }
                float rm = 1e30f;
                if (Lx > 0)      rm = fminf(rm, qx - (float)Lx * cs);
                if (Hx < GR - 1) rm = fminf(rm, (float)(Hx + 1) * cs - qx);
                if (Ly > 0)      rm = fminf(rm, qy - (float)Ly * cs);
                if (Hy < GR - 1) rm = fminf(rm, (float)(Hy + 1) * cs - qy);
                if (Lz > 0)      rm = fminf(rm, qz - (float)Lz * cs);
                if (Hz < GR - 1) rm = fminf(rm, (float)(Hz + 1) * cs - qz);
                const bool full = (Lx == 0 && Ly == 0 && Lz == 0 &&
                                   Hx == GR - 1 && Hy == GR - 1 &&
                                   Hz == GR - 1);
                if (full || d2 <= rm * rm) break;
            }
        }
    }

    // Fused epilogue: softmax(-d) + weighted feature gather (float2/lane).
    float w1 = expf(d0 - d1);
    float w2 = expf(d0 - d2);
    const float inv = 1.0f / (1.0f + w1 + w2);
    const float w0 = inv;
    w1 *= inv; w2 *= inv;

    const float2 a  = feat2[(size_t)(i0 + c * NN) * 16 + t];
    const float2 b  = feat2[(size_t)(i1 + c * NN) * 16 + t];
    const float2 gg = feat2[(size_t)(i2 + c * NN) * 16 + t];
    float2 o;
    o.x = w0 * a.x + w1 * b.x + w2 * gg.x;
    o.y = w0 * a.y + w1 * b.y + w2 * gg.y;
    out2[(size_t)m * 16 + t] = o;              // natural order -> coalesced
}

extern "C" void kernel_launch(void* const* d_in, const int* in_sizes, int n_in,
                              void* d_out, int out_size, void* d_ws, size_t ws_size,
                              hipStream_t stream) {
    const float* feat   = (const float*)d_in[0];   // points_feat [1, C*N, D] f32
    const float* verts  = (const float*)d_in[1];   // vertices    [C, N, 3]  f32
    const float* nverts = (const float*)d_in[2];   // new_vertices[C, M, 3]  f32
    float* outp = (float*)d_out;                   // [1, C*M, D] f32

    k_all<<<dim3(CC * MM / QPB), dim3(BLK), 0, stream>>>(
        (const float2*)feat, verts, nverts, (float2*)outp);
}